// Round 9
// baseline (208.657 us; speedup 1.0000x reference)
//
#include <hip/hip_runtime.h>
#include <hip/hip_bf16.h>

typedef unsigned int u32;
typedef unsigned short u16;
using f32x4  = __attribute__((ext_vector_type(4))) float;
using f32x16 = __attribute__((ext_vector_type(16))) float;
using u32x4  = __attribute__((ext_vector_type(4))) u32;
using s16x8  = __attribute__((ext_vector_type(8))) short;

#define DEV static __device__ __forceinline__

DEV u32 pk2(float a, float b) {
  u16 lo = __builtin_bit_cast(u16, __float2bfloat16(a));
  u16 hi = __builtin_bit_cast(u16, __float2bfloat16(b));
  return (u32)lo | ((u32)hi << 16);
}

DEV f32x16 MFMA32(u32x4 a, u32x4 b, f32x16 c) {
  return __builtin_amdgcn_mfma_f32_32x32x16_bf16(
      __builtin_bit_cast(s16x8, a), __builtin_bit_cast(s16x8, b), c, 0, 0, 0);
}

DEV void pl32swap(u32& a, u32& b) {
  asm volatile("v_permlane32_swap_b32 %0, %1" : "+v"(a), "+v"(b));
}

typedef const __attribute__((address_space(1))) u32 gu32;
typedef __attribute__((address_space(3))) u32 lu32;

DEV void load_lds16(const void* g, void* l) {
  __builtin_amdgcn_global_load_lds((gu32*)g, (lu32*)l, 16, 0, 0);
}

// -------- k1: per-expert alpha = mean(|W|); block 0 also zeroes the histogram
__global__ void qalpha(const float* __restrict__ w1, const float* __restrict__ w2,
                       float* __restrict__ alphas, u32* __restrict__ hist) {
  int b = blockIdx.x;
  int tid = threadIdx.x;
  if (b == 0) hist[tid] = 0;
  const float* src = (b < 8 ? w1 : w2) + (size_t)(b & 7) * 32768;
  float s = 0.f;
  for (int i = tid; i < 32768; i += 256) s += fabsf(src[i]);
  #pragma unroll
  for (int off = 32; off >= 1; off >>= 1) s += __shfl_down(s, off, 64);
  __shared__ float ws4[4];
  if ((tid & 63) == 0) ws4[tid >> 6] = s;
  __syncthreads();
  if (tid == 0) alphas[b] = (ws4[0] + ws4[1] + ws4[2] + ws4[3]) * (1.f / 32768.f);
}

DEV u16 tq1(float v, float thr) {
  return (fabsf(v) > thr) ? (v > 0.f ? (u16)0x3F80 : (u16)0xBF80) : (u16)0;
}
DEV u32 tq2(float a, float b, float thr) {
  return (u32)tq1(a, thr) | ((u32)tq1(b, thr) << 16);
}

// -------- k2: weight image (blocks <256) + gate/mask/hist (blocks >=256) --------
// img layout identical to v8 (fragment-planar, proven).
__global__ void qimg_gate(const float* __restrict__ w1, const float* __restrict__ w2,
                          const float* __restrict__ alphas, char* __restrict__ img,
                          const float* __restrict__ x, const float* __restrict__ wg,
                          const float* __restrict__ bg, float* __restrict__ gw,
                          u32* __restrict__ maskA, u32* __restrict__ hist) {
  const int tid = threadIdx.x;
  if (blockIdx.x < 256) {
    int gid = blockIdx.x * 256 + tid;  // 65536 weight items
    int l = gid & 63;
    int col = l & 31, hi = l >> 5;
    const float* src;
    float thr;
    char* dst;
    if (gid < 32768) {
      int ks = (gid >> 6) & 7;
      int n  = gid >> 9;
      int e  = n >> 3, ht = n & 7;
      int h  = ht * 32 + col;
      int k0 = ks * 16 + hi * 8;
      src = w1 + (size_t)e * 32768 + h * 128 + k0;
      thr = 0.5f * alphas[e];
      dst = img + (size_t)n * 16384 + ks * 1024 + l * 16;
    } else {
      int id = gid - 32768;
      int sl = (id >> 6) & 7;
      int n  = id >> 9;
      int e  = n >> 3, c = n & 7;
      int ks2 = sl >> 2, ot = sl & 3;
      int o  = ot * 32 + col;
      int k0 = c * 32 + ks2 * 16 + hi * 8;
      src = w2 + (size_t)e * 32768 + o * 256 + k0;
      thr = 0.5f * alphas[8 + e];
      dst = img + (size_t)n * 16384 + 8192 + sl * 1024 + l * 16;
    }
    float4 v0 = *(const float4*)src;
    float4 v1 = *(const float4*)(src + 4);
    *(uint4*)dst = make_uint4(tq2(v0.x, v0.y, thr), tq2(v0.z, v0.w, thr),
                              tq2(v1.x, v1.y, thr), tq2(v1.z, v1.w, thr));
    return;
  }
  // ---- gate for token t (exact v8 math)
  __shared__ u32 lh[256];
  lh[tid] = 0;
  int t = (blockIdx.x - 256) * 256 + tid;
  const float4* xr = (const float4*)(x + (size_t)t * 128);
  const float4* wr = (const float4*)wg;
  float lg[8];
  #pragma unroll
  for (int e = 0; e < 8; ++e) lg[e] = bg[e];
  for (int i = 0; i < 32; ++i) {
    float4 xv = xr[i];
    #pragma unroll
    for (int e = 0; e < 8; ++e) {
      float4 wv = wr[e * 32 + i];
      lg[e] += xv.x * wv.x + xv.y * wv.y + xv.z * wv.z + xv.w * wv.w;
    }
  }
  const float invT = 0.36787944117144233f;  // 1/e
  #pragma unroll
  for (int e = 0; e < 8; ++e) lg[e] *= invT;
  float mx = lg[0];
  #pragma unroll
  for (int e = 1; e < 8; ++e) mx = fmaxf(mx, lg[e]);
  float p[8], den = 0.f;
  #pragma unroll
  for (int e = 0; e < 8; ++e) { p[e] = __expf(lg[e] - mx); den += p[e]; }
  float inv = 1.f / den;
  #pragma unroll
  for (int e = 0; e < 8; ++e) p[e] *= inv;
  float gsel[8], wsum = 0.f;
  u32 m = 0;
  #pragma unroll
  for (int e = 0; e < 8; ++e) {
    int rank = 0;
    #pragma unroll
    for (int e2 = 0; e2 < 8; ++e2)
      rank += (p[e2] > p[e]) || (p[e2] == p[e] && e2 < e);
    bool sel = rank < 5;
    if (sel) m |= 1u << e;
    gsel[e] = sel ? p[e] : 0.f;
    wsum += gsel[e];
  }
  float r = 1.f / (wsum + 1e-8f);
  float* gwp = gw + (size_t)t * 8;
  *(f32x4*)gwp       = (f32x4){gsel[0] * r, gsel[1] * r, gsel[2] * r, gsel[3] * r};
  *(f32x4*)(gwp + 4) = (f32x4){gsel[4] * r, gsel[5] * r, gsel[6] * r, gsel[7] * r};
  maskA[t] = m;
  __syncthreads();
  atomicAdd(&lh[m], 1u);
  __syncthreads();
  if (lh[tid]) atomicAdd(&hist[tid], lh[tid]);
}

// -------- k3: exclusive scan of 256-bin histogram -> bin cursors --------
__global__ void kscan(const u32* __restrict__ hist, u32* __restrict__ cur) {
  __shared__ u32 s[256];
  int t = threadIdx.x;
  u32 own = hist[t];
  s[t] = own;
  __syncthreads();
  #pragma unroll
  for (int o = 1; o < 256; o <<= 1) {
    u32 v = (t >= o) ? s[t - o] : 0u;
    __syncthreads();
    s[t] += v;
    __syncthreads();
  }
  cur[t] = s[t] - own;  // exclusive prefix
}

// -------- k4: two-level counting-sort scatter -> perm --------
__global__ void kscatter(const u32* __restrict__ maskA, u32* __restrict__ cur,
                         u32* __restrict__ perm) {
  __shared__ u32 lh[256], lb[256];
  const int tid = threadIdx.x;
  int t = blockIdx.x * 256 + tid;
  u32 m = maskA[t];
  lh[tid] = 0;
  __syncthreads();
  u32 r = atomicAdd(&lh[m], 1u);
  __syncthreads();
  if (lh[tid]) lb[tid] = atomicAdd(&cur[tid], lh[tid]);
  __syncthreads();
  perm[lb[m] + r] = t;
}

// ---------------- main fused kernel (v8 structure + expert routing) ----------------
// 256 thr = 4 waves x 64 sorted tokens (tt=2), 2 blocks/CU.
// LDS: dbuf 2x32K | b1 f32 8K | gate f32 8K (union scratch overlaps) = 80K.
#define B1_OFF 65536
#define G_OFF  73728
#define SMEM_BYTES 81920

__global__ __launch_bounds__(256, 2) void moe_main(
    const float* __restrict__ x, const float* __restrict__ b1g,
    const float* __restrict__ b2g, const char* __restrict__ img,
    const u32* __restrict__ perm, const u32* __restrict__ maskA,
    const float* __restrict__ gw, float* __restrict__ out) {
  extern __shared__ char smem[];
  float* s_b1 = (float*)(smem + B1_OFF);  // [8 e][256 h] f32
  float* s_g  = (float*)(smem + G_OFF);   // [8 e][256 t] f32
  u32*   s_u  = (u32*)(smem + G_OFF);     // union scratch (overlaps s_g, phased)
  const int tid = threadIdx.x;
  const int w = tid >> 6, l = tid & 63;
  const int col = l & 31, hi = l >> 5;
  const int base = blockIdx.x * 256;
  const u32 loff = (u32)(l * 16);

  // ---- phase A: permutation, masks, block expert-union
  const u32 ptg = perm[base + tid];
  const u32 pt0 = perm[base + w * 64 + col];
  const u32 pt1 = perm[base + w * 64 + 32 + col];
  s_u[tid] = maskA[ptg];
  __syncthreads();
  #pragma unroll
  for (int st = 128; st >= 1; st >>= 1) {
    if (tid < st) s_u[tid] |= s_u[tid + st];
    __syncthreads();
  }
  const u32 bmask = s_u[0];
  __syncthreads();  // union reads done before s_g overwrite

  // build packed expert list (ascending)
  u32 elist = 0;
  int cnt = 0;
  #pragma unroll
  for (int e = 0; e < 8; ++e)
    if ((bmask >> e) & 1) { elist |= (u32)e << (4 * cnt); ++cnt; }

  // stage absolute chunk-pair P into slot; 8KB per wave
  auto stage_pair = [&](int P, int slot) {
    const char* src = img + (size_t)P * 32768 + w * 8192 + loff;
    char* dst = smem + slot * 32768 + w * 8192;
    #pragma unroll
    for (int i = 0; i < 8; ++i)
      load_lds16(src + i * 1024, dst + i * 1024);
  };

  // issue first stage ASAP (latency hides under the fills below)
  stage_pair((elist & 7) * 4, 0);

  // ---- fill s_g (gathered gate weights), b1 copy
  {
    f32x4 gA = *(const f32x4*)(gw + (size_t)ptg * 8);
    f32x4 gB = *(const f32x4*)(gw + (size_t)ptg * 8 + 4);
    s_g[0 * 256 + tid] = gA.x; s_g[1 * 256 + tid] = gA.y;
    s_g[2 * 256 + tid] = gA.z; s_g[3 * 256 + tid] = gA.w;
    s_g[4 * 256 + tid] = gB.x; s_g[5 * 256 + tid] = gB.y;
    s_g[6 * 256 + tid] = gB.z; s_g[7 * 256 + tid] = gB.w;
    const float4* s = (const float4*)b1g;
    float4* d = (float4*)s_b1;
    d[tid] = s[tid];
    d[tid + 256] = s[tid + 256];
  }

  // ---- xf: gathered x fragments (rows pt0/pt1), bf16, in regs all kernel
  u32x4 xf[2][8];
  #pragma unroll
  for (int tt = 0; tt < 2; ++tt) {
    const u32 pt = tt ? pt1 : pt0;
    #pragma unroll
    for (int ks = 0; ks < 8; ++ks) {
      const float* xp = x + (size_t)pt * 128 + ks * 16 + hi * 8;
      float4 v0 = *(const float4*)xp;
      float4 v1 = *(const float4*)(xp + 4);
      xf[tt][ks] = (u32x4){pk2(v0.x, v0.y), pk2(v0.z, v0.w),
                           pk2(v1.x, v1.y), pk2(v1.z, v1.w)};
    }
  }
  __syncthreads();  // s_g + b1 visible; drains stage0

  // ---- init acc2[ot][tt] = sum_e g[t][e]*b2[e][o] via one K=16 MFMA pass
  f32x16 acc2[4][2];
  {
    u32x4 gf[2];
    #pragma unroll
    for (int tt = 0; tt < 2; ++tt) {
      u32x4 v = (u32x4){0u, 0u, 0u, 0u};
      if (hi == 0) {
        int t = w * 64 + tt * 32 + col;
        v = (u32x4){pk2(s_g[0 * 256 + t], s_g[1 * 256 + t]),
                    pk2(s_g[2 * 256 + t], s_g[3 * 256 + t]),
                    pk2(s_g[4 * 256 + t], s_g[5 * 256 + t]),
                    pk2(s_g[6 * 256 + t], s_g[7 * 256 + t])};
      }
      gf[tt] = v;
    }
    #pragma unroll
    for (int ot = 0; ot < 4; ++ot) {
      u32x4 af = (u32x4){0u, 0u, 0u, 0u};
      if (hi == 0) {
        int o = ot * 32 + col;
        af = (u32x4){pk2(b2g[0 * 128 + o], b2g[1 * 128 + o]),
                     pk2(b2g[2 * 128 + o], b2g[3 * 128 + o]),
                     pk2(b2g[4 * 128 + o], b2g[5 * 128 + o]),
                     pk2(b2g[6 * 128 + o], b2g[7 * 128 + o])};
      }
      f32x16 z{};
      #pragma unroll
      for (int tt = 0; tt < 2; ++tt) acc2[ot][tt] = MFMA32(af, gf[tt], z);
    }
  }

  // ---- one chunk (tt=2): G1 16 MFMA -> EPI -> G2 16 MFMA (v8-proven)
  auto chunk = [&](const char* cb, int e, int ht, float g0, float g1) {
    f32x16 a1_0{}, a1_1{};
    __builtin_amdgcn_s_setprio(1);
    #pragma unroll
    for (int ks = 0; ks < 8; ++ks) {
      u32x4 f = *(const u32x4*)(cb + ks * 1024 + loff);
      a1_0 = MFMA32(f, xf[0][ks], a1_0);
      a1_1 = MFMA32(f, xf[1][ks], a1_1);
    }
    __builtin_amdgcn_s_setprio(0);

    const float* b1b = s_b1 + e * 256 + ht * 32 + hi * 4;
    u32x4 hf[2][2];
    #pragma unroll
    for (int tt = 0; tt < 2; ++tt) {
      const f32x16& a1 = tt ? a1_1 : a1_0;
      const float g = tt ? g1 : g0;
      u32 u[8];
      #pragma unroll
      for (int rg = 0; rg < 4; ++rg) {
        f32x4 bb = *(const f32x4*)(b1b + rg * 8);
        float h0 = fmaxf(a1[rg * 4 + 0] + bb.x, 0.f) * g;
        float h1 = fmaxf(a1[rg * 4 + 1] + bb.y, 0.f) * g;
        float h2 = fmaxf(a1[rg * 4 + 2] + bb.z, 0.f) * g;
        float h3 = fmaxf(a1[rg * 4 + 3] + bb.w, 0.f) * g;
        u[rg * 2 + 0] = pk2(h0, h1);
        u[rg * 2 + 1] = pk2(h2, h3);
      }
      pl32swap(u[0], u[2]);
      pl32swap(u[1], u[3]);
      pl32swap(u[4], u[6]);
      pl32swap(u[5], u[7]);
      hf[0][tt] = (u32x4){u[0], u[1], u[2], u[3]};
      hf[1][tt] = (u32x4){u[4], u[5], u[6], u[7]};
    }

    __builtin_amdgcn_s_setprio(1);
    #pragma unroll
    for (int ks2 = 0; ks2 < 2; ++ks2) {
      #pragma unroll
      for (int ot = 0; ot < 4; ++ot) {
        u32x4 af = *(const u32x4*)(cb + 8192 + (ks2 * 4 + ot) * 1024 + loff);
        acc2[ot][0] = MFMA32(af, hf[ks2][0], acc2[ot][0]);
        acc2[ot][1] = MFMA32(af, hf[ks2][1], acc2[ot][1]);
      }
    }
    __builtin_amdgcn_s_setprio(0);
  };

  // ---- main loop over active experts only: iters = cnt*4 chunk-pairs
  const int iters = cnt * 4;
  #pragma unroll 1
  for (int i = 0; i < iters; ++i) {
    asm volatile("s_waitcnt vmcnt(0)" ::: "memory");
    __builtin_amdgcn_s_barrier();
    __builtin_amdgcn_sched_barrier(0);
    if (i + 1 < iters) {
      const int j = i + 1;
      const int ej = (elist >> (4 * (j >> 2))) & 7;
      stage_pair(ej * 4 + (j & 3), j & 1);
    }
    const int ei = (elist >> (4 * (i >> 2))) & 7;
    const int ht0 = (i & 3) * 2;
    const float g0 = s_g[ei * 256 + w * 64 + col];
    const float g1 = s_g[ei * 256 + w * 64 + 32 + col];
    const char* buf = smem + (i & 1) * 32768;
    chunk(buf, ei, ht0, g0, g1);
    __builtin_amdgcn_sched_barrier(0);  // no cross-chunk frag hoisting (spill guard)
    chunk(buf + 16384, ei, ht0 + 1, g0, g1);
  }

  // ---- store D2[o][t] -> out rows pt0/pt1
  #pragma unroll
  for (int ot = 0; ot < 4; ++ot) {
    #pragma unroll
    for (int tt = 0; tt < 2; ++tt) {
      const f32x16& a = acc2[ot][tt];
      float* op = out + (size_t)(tt ? pt1 : pt0) * 128 + ot * 32 + hi * 4;
      #pragma unroll
      for (int rg = 0; rg < 4; ++rg)
        *(f32x4*)(op + rg * 8) =
            (f32x4){a[rg * 4 + 0], a[rg * 4 + 1], a[rg * 4 + 2], a[rg * 4 + 3]};
    }
  }
}

extern "C" void kernel_launch(void* const* d_in, const int* in_sizes, int n_in,
                              void* d_out, int out_size, void* d_ws, size_t ws_size,
                              hipStream_t stream) {
  const float* x  = (const float*)d_in[0];
  const float* w1 = (const float*)d_in[1];
  const float* b1 = (const float*)d_in[2];
  const float* w2 = (const float*)d_in[3];
  const float* b2 = (const float*)d_in[4];
  const float* wg = (const float*)d_in[5];
  const float* bg = (const float*)d_in[6];
  float* out = (float*)d_out;

  // ws layout (bytes)
  char* ws = (char*)d_ws;
  char*  img    = ws;                          // 1 MB weight image
  float* alphas = (float*)(ws + 1048576);      // 64 B
  u32*   hist   = (u32*)(ws + 1048640);        // 1 KB
  u32*   cur    = (u32*)(ws + 1049664);        // 1 KB
  u32*   maskA  = (u32*)(ws + 1050688);        // 512 KB
  u32*   perm   = (u32*)(ws + 1574976);        // 512 KB
  float* gw     = (float*)(ws + 2099264);      // 4 MB
  if (ws_size < 6293568) return;

  int ntok = in_sizes[0] / 128;
  int nblk = ntok / 256;

  qalpha<<<16, 256, 0, stream>>>(w1, w2, alphas, hist);
  qimg_gate<<<256 + nblk, 256, 0, stream>>>(w1, w2, alphas, img, x, wg, bg,
                                            gw, maskA, hist);
  kscan<<<1, 256, 0, stream>>>(hist, cur);
  kscatter<<<nblk, 256, 0, stream>>>(maskA, cur, perm);

  hipFuncSetAttribute(reinterpret_cast<const void*>(moe_main),
                      hipFuncAttributeMaxDynamicSharedMemorySize, SMEM_BYTES);
  moe_main<<<nblk, 256, SMEM_BYTES, stream>>>(x, b1, b2, img, perm, maskA, gw, out);
}

// Round 10
// 189.140 us; speedup vs baseline: 1.1032x; 1.1032x over previous
//
#include <hip/hip_runtime.h>
#include <hip/hip_bf16.h>

typedef unsigned int u32;
typedef unsigned short u16;
using f32x4  = __attribute__((ext_vector_type(4))) float;
using f32x16 = __attribute__((ext_vector_type(16))) float;
using u32x4  = __attribute__((ext_vector_type(4))) u32;
using s16x8  = __attribute__((ext_vector_type(8))) short;

#define DEV static __device__ __forceinline__
#define SKIP 0xFFFFFFFFu

DEV u32 pk2(float a, float b) {
  u16 lo = __builtin_bit_cast(u16, __float2bfloat16(a));
  u16 hi = __builtin_bit_cast(u16, __float2bfloat16(b));
  return (u32)lo | ((u32)hi << 16);
}

DEV f32x16 MFMA32(u32x4 a, u32x4 b, f32x16 c) {
  return __builtin_amdgcn_mfma_f32_32x32x16_bf16(
      __builtin_bit_cast(s16x8, a), __builtin_bit_cast(s16x8, b), c, 0, 0, 0);
}

DEV void pl32swap(u32& a, u32& b) {
  asm volatile("v_permlane32_swap_b32 %0, %1" : "+v"(a), "+v"(b));
}

typedef const __attribute__((address_space(1))) u32 gu32;
typedef __attribute__((address_space(3))) u32 lu32;

DEV void load_lds16(const void* g, void* l) {
  __builtin_amdgcn_global_load_lds((gu32*)g, (lu32*)l, 16, 0, 0);
}

// -------- k1: per-expert alpha = mean(|W|); block 0 zeroes hist + cur2 --------
__global__ void qalpha(const float* __restrict__ w1, const float* __restrict__ w2,
                       float* __restrict__ alphas, u32* __restrict__ hist,
                       u32* __restrict__ cur2) {
  int b = blockIdx.x;
  int tid = threadIdx.x;
  if (b == 0) { hist[tid] = 0; cur2[tid] = 0; }
  const float* src = (b < 8 ? w1 : w2) + (size_t)(b & 7) * 32768;
  float s = 0.f;
  for (int i = tid; i < 32768; i += 256) s += fabsf(src[i]);
  #pragma unroll
  for (int off = 32; off >= 1; off >>= 1) s += __shfl_down(s, off, 64);
  __shared__ float ws4[4];
  if ((tid & 63) == 0) ws4[tid >> 6] = s;
  __syncthreads();
  if (tid == 0) alphas[b] = (ws4[0] + ws4[1] + ws4[2] + ws4[3]) * (1.f / 32768.f);
}

DEV u16 tq1(float v, float thr) {
  return (fabsf(v) > thr) ? (v > 0.f ? (u16)0x3F80 : (u16)0xBF80) : (u16)0;
}
DEV u32 tq2(float a, float b, float thr) {
  return (u32)tq1(a, thr) | ((u32)tq1(b, thr) << 16);
}

// -------- k2: weight image (blocks <256) + gate/mask/hist (blocks >=256) --------
__global__ void qimg_gate(const float* __restrict__ w1, const float* __restrict__ w2,
                          const float* __restrict__ alphas, char* __restrict__ img,
                          const float* __restrict__ x, const float* __restrict__ wg,
                          const float* __restrict__ bg, float* __restrict__ gw,
                          u32* __restrict__ maskA, u32* __restrict__ hist) {
  const int tid = threadIdx.x;
  if (blockIdx.x < 256) {
    int gid = blockIdx.x * 256 + tid;  // 65536 weight items
    int l = gid & 63;
    int col = l & 31, hi = l >> 5;
    const float* src;
    float thr;
    char* dst;
    if (gid < 32768) {
      int ks = (gid >> 6) & 7;
      int n  = gid >> 9;
      int e  = n >> 3, ht = n & 7;
      int h  = ht * 32 + col;
      int k0 = ks * 16 + hi * 8;
      src = w1 + (size_t)e * 32768 + h * 128 + k0;
      thr = 0.5f * alphas[e];
      dst = img + (size_t)n * 16384 + ks * 1024 + l * 16;
    } else {
      int id = gid - 32768;
      int sl = (id >> 6) & 7;
      int n  = id >> 9;
      int e  = n >> 3, c = n & 7;
      int ks2 = sl >> 2, ot = sl & 3;
      int o  = ot * 32 + col;
      int k0 = c * 32 + ks2 * 16 + hi * 8;
      src = w2 + (size_t)e * 32768 + o * 256 + k0;
      thr = 0.5f * alphas[8 + e];
      dst = img + (size_t)n * 16384 + 8192 + sl * 1024 + l * 16;
    }
    float4 v0 = *(const float4*)src;
    float4 v1 = *(const float4*)(src + 4);
    *(uint4*)dst = make_uint4(tq2(v0.x, v0.y, thr), tq2(v0.z, v0.w, thr),
                              tq2(v1.x, v1.y, thr), tq2(v1.z, v1.w, thr));
    return;
  }
  // ---- gate for token t (exact v8/v9 math)
  __shared__ u32 lh[256];
  lh[tid] = 0;
  int t = (blockIdx.x - 256) * 256 + tid;
  const float4* xr = (const float4*)(x + (size_t)t * 128);
  const float4* wr = (const float4*)wg;
  float lg[8];
  #pragma unroll
  for (int e = 0; e < 8; ++e) lg[e] = bg[e];
  for (int i = 0; i < 32; ++i) {
    float4 xv = xr[i];
    #pragma unroll
    for (int e = 0; e < 8; ++e) {
      float4 wv = wr[e * 32 + i];
      lg[e] += xv.x * wv.x + xv.y * wv.y + xv.z * wv.z + xv.w * wv.w;
    }
  }
  const float invT = 0.36787944117144233f;  // 1/e
  #pragma unroll
  for (int e = 0; e < 8; ++e) lg[e] *= invT;
  float mx = lg[0];
  #pragma unroll
  for (int e = 1; e < 8; ++e) mx = fmaxf(mx, lg[e]);
  float p[8], den = 0.f;
  #pragma unroll
  for (int e = 0; e < 8; ++e) { p[e] = __expf(lg[e] - mx); den += p[e]; }
  float inv = 1.f / den;
  #pragma unroll
  for (int e = 0; e < 8; ++e) p[e] *= inv;
  float gsel[8], wsum = 0.f;
  u32 m = 0;
  #pragma unroll
  for (int e = 0; e < 8; ++e) {
    int rank = 0;
    #pragma unroll
    for (int e2 = 0; e2 < 8; ++e2)
      rank += (p[e2] > p[e]) || (p[e2] == p[e] && e2 < e);
    bool sel = rank < 5;
    if (sel) m |= 1u << e;
    gsel[e] = sel ? p[e] : 0.f;
    wsum += gsel[e];
  }
  float r = 1.f / (wsum + 1e-8f);
  float* gwp = gw + (size_t)t * 8;
  *(f32x4*)gwp       = (f32x4){gsel[0] * r, gsel[1] * r, gsel[2] * r, gsel[3] * r};
  *(f32x4*)(gwp + 4) = (f32x4){gsel[4] * r, gsel[5] * r, gsel[6] * r, gsel[7] * r};
  maskA[t] = m;
  __syncthreads();
  atomicAdd(&lh[m], 1u);
  __syncthreads();
  if (lh[tid]) atomicAdd(&hist[tid], lh[tid]);
}

// -------- k3: scatter with local padded scan (bins padded to 128-multiples) ----
__global__ void kscatter(const u32* __restrict__ hist, const u32* __restrict__ maskA,
                         u32* __restrict__ cur2, u32* __restrict__ perm,
                         u32* __restrict__ ptotal) {
  __shared__ u32 s[256], lh[256], lb[256];
  const int t = threadIdx.x;
  u32 h = hist[t];
  u32 pad = (h + 127u) & ~127u;
  s[t] = pad;
  lh[t] = 0;
  __syncthreads();
  #pragma unroll
  for (int o = 1; o < 256; o <<= 1) {
    u32 v = (t >= o) ? s[t - o] : 0u;
    __syncthreads();
    s[t] += v;
    __syncthreads();
  }
  if (blockIdx.x == 0 && t == 255) *ptotal = s[255];
  const u32 pbase = s[t] - pad;  // exclusive padded prefix for bin t
  int tkn = blockIdx.x * 256 + t;
  u32 m = maskA[tkn];
  u32 r = atomicAdd(&lh[m], 1u);
  __syncthreads();
  if (lh[t]) lb[t] = pbase + atomicAdd(&cur2[t], lh[t]);
  __syncthreads();
  perm[lb[m] + r] = (u32)tkn;
}

// ---------------- main fused kernel ----------------
// 256 thr = 4 waves x 32 tokens (tt=1) = 128 sorted tokens/block; 3 blocks/CU.
// Every block is single-mask (bins padded to 128) -> uniform 5 experts x 8 chunks.
// LDS: dbuf 2x16K | b1 f32 8K | gate f32 4K = 44K (3 blocks = 132K).
#define B1_OFF 32768
#define G_OFF  40960
#define SMEM_BYTES 45056

__global__ __launch_bounds__(256, 3) void moe_main(
    const float* __restrict__ x, const float* __restrict__ b1g,
    const float* __restrict__ b2g, const char* __restrict__ img,
    const u32* __restrict__ perm, const u32* __restrict__ maskA,
    const float* __restrict__ gw, const u32* __restrict__ ptotal,
    float* __restrict__ out) {
  extern __shared__ char smem[];
  float* s_b1 = (float*)(smem + B1_OFF);  // [8 e][256 h] f32
  float* s_g  = (float*)(smem + G_OFF);   // [8 e][128 t] f32
  const int tid = threadIdx.x;
  const int w = tid >> 6, l = tid & 63;
  const int col = l & 31, hi = l >> 5;
  const int base = blockIdx.x * 128;
  if ((u32)base >= *ptotal) return;  // beyond padded token count
  const u32 loff = (u32)(l * 16);

  // ---- routing: this block is pure (single mask); first slot is always real
  const u32 pt = perm[base + w * 32 + col];          // this lane-pair's token
  const u32 ptc = (pt == SKIP) ? 0u : pt;
  const u32 bmask = maskA[perm[base]];
  u32 elist = 0;
  int cnt = 0;
  #pragma unroll
  for (int e = 0; e < 8; ++e)
    if ((bmask >> e) & 1) { elist |= (u32)e << (4 * cnt); ++cnt; }

  // stage chunk n (16KB) into slot; 4KB per wave
  auto stage = [&](int n, int slot) {
    const char* src = img + (size_t)n * 16384 + w * 4096 + loff;
    char* dst = smem + slot * 16384 + w * 4096;
    #pragma unroll
    for (int i = 0; i < 4; ++i)
      load_lds16(src + i * 1024, dst + i * 1024);
  };

  stage((elist & 7) * 8, 0);  // first chunk; latency hides under fills below

  // ---- s_g fill (gathered gate weights; 2 threads per token)
  {
    int tok = tid >> 1;
    u32 p2 = perm[base + tok];
    u32 p2c = (p2 == SKIP) ? 0u : p2;
    f32x4 g = ((const f32x4*)(gw + (size_t)p2c * 8))[tid & 1];
    int e0 = (tid & 1) * 4;
    s_g[(e0 + 0) * 128 + tok] = g.x;
    s_g[(e0 + 1) * 128 + tok] = g.y;
    s_g[(e0 + 2) * 128 + tok] = g.z;
    s_g[(e0 + 3) * 128 + tok] = g.w;
  }
  // ---- b1 f32 -> LDS (8KB)
  {
    const float4* s = (const float4*)b1g;
    float4* d = (float4*)s_b1;
    d[tid] = s[tid];
    d[tid + 256] = s[tid + 256];
  }
  // ---- xf: gathered x fragments (row ptc), bf16, in regs all kernel
  u32x4 xf[8];
  #pragma unroll
  for (int ks = 0; ks < 8; ++ks) {
    const float* xp = x + (size_t)ptc * 128 + ks * 16 + hi * 8;
    float4 v0 = *(const float4*)xp;
    float4 v1 = *(const float4*)(xp + 4);
    xf[ks] = (u32x4){pk2(v0.x, v0.y), pk2(v0.z, v0.w),
                     pk2(v1.x, v1.y), pk2(v1.z, v1.w)};
  }
  __syncthreads();  // s_g + b1 visible; drains first stage

  // ---- init acc2[ot] = sum_e g[t][e]*b2[e][o] via one K=16 MFMA pass
  f32x16 acc2[4];
  {
    u32x4 gf = (u32x4){0u, 0u, 0u, 0u};
    if (hi == 0) {
      int t = w * 32 + col;
      gf = (u32x4){pk2(s_g[0 * 128 + t], s_g[1 * 128 + t]),
                   pk2(s_g[2 * 128 + t], s_g[3 * 128 + t]),
                   pk2(s_g[4 * 128 + t], s_g[5 * 128 + t]),
                   pk2(s_g[6 * 128 + t], s_g[7 * 128 + t])};
    }
    #pragma unroll
    for (int ot = 0; ot < 4; ++ot) {
      u32x4 af = (u32x4){0u, 0u, 0u, 0u};
      if (hi == 0) {
        int o = ot * 32 + col;
        af = (u32x4){pk2(b2g[0 * 128 + o], b2g[1 * 128 + o]),
                     pk2(b2g[2 * 128 + o], b2g[3 * 128 + o]),
                     pk2(b2g[4 * 128 + o], b2g[5 * 128 + o]),
                     pk2(b2g[6 * 128 + o], b2g[7 * 128 + o])};
      }
      f32x16 z{};
      acc2[ot] = MFMA32(af, gf, z);
    }
  }

  // ---- main loop: 40 iters (5 experts x 8 chunks), 1 barrier per 16 MFMA;
  //      3 blocks/CU provide cross-block overlap of the barrier stalls.
  const int iters = cnt * 8;
  #pragma unroll 1
  for (int i = 0; i < iters; ++i) {
    asm volatile("s_waitcnt vmcnt(0)" ::: "memory");  // stage from i-1 landed
    __builtin_amdgcn_s_barrier();
    __builtin_amdgcn_sched_barrier(0);
    if (i + 1 < iters) {
      const int j = i + 1;
      const int ej = (elist >> (4 * (j >> 3))) & 7;
      stage(ej * 8 + (j & 7), j & 1);
    }
    const int e  = (elist >> (4 * (i >> 3))) & 7;
    const int ht = i & 7;
    const char* cb = smem + (i & 1) * 16384;

    // --- GEMM1: 8 MFMA
    f32x16 a1{};
    __builtin_amdgcn_s_setprio(1);
    #pragma unroll
    for (int ks = 0; ks < 8; ++ks) {
      u32x4 f = *(const u32x4*)(cb + ks * 1024 + loff);
      a1 = MFMA32(f, xf[ks], a1);
    }
    __builtin_amdgcn_s_setprio(0);

    // --- epilogue: +b1, relu, *gate, pack, permlane
    const float g = s_g[e * 128 + w * 32 + col];
    const float* b1b = s_b1 + e * 256 + ht * 32 + hi * 4;
    u32 u[8];
    #pragma unroll
    for (int rg = 0; rg < 4; ++rg) {
      f32x4 bb = *(const f32x4*)(b1b + rg * 8);
      float h0 = fmaxf(a1[rg * 4 + 0] + bb.x, 0.f) * g;
      float h1 = fmaxf(a1[rg * 4 + 1] + bb.y, 0.f) * g;
      float h2 = fmaxf(a1[rg * 4 + 2] + bb.z, 0.f) * g;
      float h3 = fmaxf(a1[rg * 4 + 3] + bb.w, 0.f) * g;
      u[rg * 2 + 0] = pk2(h0, h1);
      u[rg * 2 + 1] = pk2(h2, h3);
    }
    pl32swap(u[0], u[2]);
    pl32swap(u[1], u[3]);
    pl32swap(u[4], u[6]);
    pl32swap(u[5], u[7]);
    u32x4 hf0 = (u32x4){u[0], u[1], u[2], u[3]};
    u32x4 hf1 = (u32x4){u[4], u[5], u[6], u[7]};

    // --- GEMM2: 8 MFMA
    __builtin_amdgcn_s_setprio(1);
    #pragma unroll
    for (int ot = 0; ot < 4; ++ot)
      acc2[ot] = MFMA32(*(const u32x4*)(cb + 8192 + ot * 1024 + loff), hf0, acc2[ot]);
    #pragma unroll
    for (int ot = 0; ot < 4; ++ot)
      acc2[ot] = MFMA32(*(const u32x4*)(cb + 8192 + (4 + ot) * 1024 + loff), hf1, acc2[ot]);
    __builtin_amdgcn_s_setprio(0);
  }

  // ---- store D2[o][t] -> out row pt (skip padded slots)
  if (pt != SKIP) {
    #pragma unroll
    for (int ot = 0; ot < 4; ++ot) {
      const f32x16& a = acc2[ot];
      float* op = out + (size_t)pt * 128 + ot * 32 + hi * 4;
      #pragma unroll
      for (int rg = 0; rg < 4; ++rg)
        *(f32x4*)(op + rg * 8) =
            (f32x4){a[rg * 4 + 0], a[rg * 4 + 1], a[rg * 4 + 2], a[rg * 4 + 3]};
    }
  }
}

extern "C" void kernel_launch(void* const* d_in, const int* in_sizes, int n_in,
                              void* d_out, int out_size, void* d_ws, size_t ws_size,
                              hipStream_t stream) {
  const float* x  = (const float*)d_in[0];
  const float* w1 = (const float*)d_in[1];
  const float* b1 = (const float*)d_in[2];
  const float* w2 = (const float*)d_in[3];
  const float* b2 = (const float*)d_in[4];
  const float* wg = (const float*)d_in[5];
  const float* bg = (const float*)d_in[6];
  float* out = (float*)d_out;

  int ntok = in_sizes[0] / 128;
  int nblk_g = ntok / 256;
  int nblk_m = ntok / 128 + 56;  // padded upper bound (<=56 mask bins)

  // ws layout (bytes)
  char* ws = (char*)d_ws;
  char*  img    = ws;                      // 1 MB weight image
  float* alphas = (float*)(ws + 1048576);  // 64 B
  u32*   hist   = (u32*)(ws + 1048640);    // 1 KB
  u32*   cur2   = (u32*)(ws + 1049664);    // 1 KB
  u32*   ptotal = (u32*)(ws + 1050688);    // 64 B
  u32*   maskA  = (u32*)(ws + 1050752);    // 512 KB
  u32*   perm   = (u32*)(ws + 1575040);    // padded perm
  size_t permsz = (size_t)nblk_m * 128 * 4;
  float* gw     = (float*)(ws + 1575040 + ((permsz + 4095) & ~(size_t)4095));
  if (ws_size < 1575040 + ((permsz + 4095) & ~(size_t)4095) + (size_t)ntok * 32)
    return;

  qalpha<<<16, 256, 0, stream>>>(w1, w2, alphas, hist, cur2);
  hipMemsetAsync(perm, 0xFF, permsz, stream);
  qimg_gate<<<256 + nblk_g, 256, 0, stream>>>(w1, w2, alphas, img, x, wg, bg,
                                              gw, maskA, hist);
  kscatter<<<nblk_g, 256, 0, stream>>>(hist, maskA, cur2, perm, ptotal);

  hipFuncSetAttribute(reinterpret_cast<const void*>(moe_main),
                      hipFuncAttributeMaxDynamicSharedMemorySize, SMEM_BYTES);
  moe_main<<<nblk_m, 256, SMEM_BYTES, stream>>>(x, b1, b2, img, perm, maskA, gw,
                                                ptotal, out);
}